// Round 4
// baseline (718.290 us; speedup 1.0000x reference)
//
#include <hip/hip_runtime.h>
#include <math.h>

// StreamingTransformerLayer on MI355X (gfx950).  Round 4.
// B=8 T=256 C=2048 H=16 Dh=128 CAP=2048 FF=8192, offset read on-device.
// R4 changes (attention only):
//  - split-S by chunk parity: grid 256->512 blocks (2/CU), partials + combine kernel
//  - V staged via column loads + XOR-swizzled linear [d][s] LDS (b128 writes at
//    conflict floor; was 32 scalar b16 writes/lane at ~8-way conflict)
//  - P relayout buffer gets the same XOR swizzle
//  - T13 defer-max (THR=8) skips O-rescale when chunk max grows < 8

typedef __bf16 bf16_t;
typedef __bf16 bf16x8 __attribute__((ext_vector_type(8)));
typedef float  f32x4  __attribute__((ext_vector_type(4)));

#define MFMA(a, b, c) __builtin_amdgcn_mfma_f32_16x16x32_bf16((a), (b), (c), 0, 0, 0)

static __device__ __forceinline__ bf16x8 cvt8(const float* __restrict__ src) {
    f32x4 f0 = *(const f32x4*)src;
    f32x4 f1 = *(const f32x4*)(src + 4);
    bf16x8 v;
    v[0] = (bf16_t)f0[0]; v[1] = (bf16_t)f0[1]; v[2] = (bf16_t)f0[2]; v[3] = (bf16_t)f0[3];
    v[4] = (bf16_t)f1[0]; v[5] = (bf16_t)f1[1]; v[6] = (bf16_t)f1[2]; v[7] = (bf16_t)f1[3];
    return v;
}

// async global->LDS, 16B per lane; lds base must be wave-uniform
static __device__ __forceinline__ void gload16(const bf16_t* g, bf16_t* lds) {
    __builtin_amdgcn_global_load_lds(
        (const __attribute__((address_space(1))) void*)g,
        (__attribute__((address_space(3))) void*)lds, 16, 0, 0);
}

// ---------------- weight convert: rows x cols, row stride (f32 -> bf16) ----------------
__global__ __launch_bounds__(256)
void cvt_rows_kernel(const float* __restrict__ src, bf16_t* __restrict__ dst,
                     int cols, int src_stride)
{
    const int row = blockIdx.x;
    const float* s = src + (size_t)row * src_stride;
    bf16_t* d = dst + (size_t)row * cols;
    for (int c = threadIdx.x * 8; c < cols; c += blockDim.x * 8)
        *(bf16x8*)&d[c] = cvt8(&s[c]);
}

// ---------------- RMSNorm: one block per row of 2048 f32, out bf16 ----------------
__global__ __launch_bounds__(256)
void rmsnorm_kernel(const float* __restrict__ x, const float* __restrict__ alpha,
                    bf16_t* __restrict__ out)
{
    const int C = 2048;
    const int row = blockIdx.x;
    const int tid = threadIdx.x;
    const float* xr = x + (size_t)row * C;
    f32x4 a0 = *(const f32x4*)&xr[tid * 8];
    f32x4 a1 = *(const f32x4*)&xr[tid * 8 + 4];
    float ss = a0[0]*a0[0] + a0[1]*a0[1] + a0[2]*a0[2] + a0[3]*a0[3]
             + a1[0]*a1[0] + a1[1]*a1[1] + a1[2]*a1[2] + a1[3]*a1[3];
    #pragma unroll
    for (int d = 32; d >= 1; d >>= 1) ss += __shfl_xor(ss, d);
    __shared__ float red[4];
    const int lane = tid & 63, wid = tid >> 6;
    if (lane == 0) red[wid] = ss;
    __syncthreads();
    const float tot = red[0] + red[1] + red[2] + red[3];
    const float rs = rsqrtf(1e-5f + tot * (1.0f / C));
    f32x4 l0 = *(const f32x4*)&alpha[tid * 8];
    f32x4 l1 = *(const f32x4*)&alpha[tid * 8 + 4];
    bf16x8 o8;
    o8[0] = (bf16_t)(a0[0] * l0[0] * rs); o8[1] = (bf16_t)(a0[1] * l0[1] * rs);
    o8[2] = (bf16_t)(a0[2] * l0[2] * rs); o8[3] = (bf16_t)(a0[3] * l0[3] * rs);
    o8[4] = (bf16_t)(a1[0] * l1[0] * rs); o8[5] = (bf16_t)(a1[1] * l1[1] * rs);
    o8[6] = (bf16_t)(a1[2] * l1[2] * rs); o8[7] = (bf16_t)(a1[3] * l1[3] * rs);
    *(bf16x8*)&out[(size_t)row * C + tid * 8] = o8;
}

// ---------------- GEMM (m97 structure): C[M,N] = A[M,K] * B[N,K]^T, both bf16 ----------------
// EPI: 0 f32 | 1 res+acc f32 | 2 gelu bf16 | 3 bf16
template<int EPI>
__global__ __launch_bounds__(256)
void gemm_bb(const bf16_t* __restrict__ A, const bf16_t* __restrict__ B,
             float* Cf, bf16_t* Cb, const float* __restrict__ res,
             int M, int N, int K)
{
    __shared__ bf16_t As[128 * 64];
    __shared__ bf16_t Bs[128 * 64];
    const int gx = gridDim.x;
    const int nwg = gx * gridDim.y;
    int bid = blockIdx.y * gx + blockIdx.x;
    bid = (bid & 7) * (nwg >> 3) + (bid >> 3);   // grids are multiples of 8
    const int n0 = (bid % gx) * 128;
    const int m0 = (bid / gx) * 128;

    const int tid = threadIdx.x;
    const int lane = tid & 63, wid = tid >> 6;
    const int wr = wid >> 1, wc = wid & 1;
    const int lr = lane & 15, lg = lane >> 4;
    const int srow = lane >> 3;
    const int scol = (lane & 7) * 8;
    f32x4 acc[4][4] = {};

    for (int kt = 0; kt < K; kt += 64) {
        __syncthreads();
        #pragma unroll
        for (int it = 0; it < 4; ++it) {
            const int r = wid * 32 + it * 8;
            gload16(&A[(size_t)(m0 + r + srow) * K + kt + scol], &As[r * 64]);
            gload16(&B[(size_t)(n0 + r + srow) * K + kt + scol], &Bs[r * 64]);
        }
        __syncthreads();
        #pragma unroll
        for (int kk = 0; kk < 2; ++kk) {
            bf16x8 af[4], bfr[4];
            #pragma unroll
            for (int m = 0; m < 4; ++m)
                af[m] = *(const bf16x8*)&As[(wr * 64 + m * 16 + lr) * 64 + kk * 32 + lg * 8];
            #pragma unroll
            for (int n = 0; n < 4; ++n)
                bfr[n] = *(const bf16x8*)&Bs[(wc * 64 + n * 16 + lr) * 64 + kk * 32 + lg * 8];
            #pragma unroll
            for (int m = 0; m < 4; ++m)
                #pragma unroll
                for (int n = 0; n < 4; ++n)
                    acc[m][n] = MFMA(af[m], bfr[n], acc[m][n]);
        }
    }
    #pragma unroll
    for (int m = 0; m < 4; ++m) {
        #pragma unroll
        for (int n = 0; n < 4; ++n) {
            const int gmb = m0 + wr * 64 + m * 16 + lg * 4;
            const int gn  = n0 + wc * 64 + n * 16 + lr;
            #pragma unroll
            for (int r = 0; r < 4; ++r) {
                const size_t off = (size_t)(gmb + r) * N + gn;
                const float v = acc[m][n][r];
                if (EPI == 0)      Cf[off] = v;
                else if (EPI == 1) Cf[off] = res[off] + v;
                else if (EPI == 2) Cb[off] = (bf16_t)(0.5f * v * (1.0f + erff(v * 0.70710678118654752f)));
                else               Cb[off] = (bf16_t)v;
            }
        }
    }
}

// ---------------- RoPE + split qkv -> q/kn/vn in [B*H][T][Dh] bf16 ----------------
__global__ __launch_bounds__(256)
void rope_split_kernel(const bf16_t* __restrict__ qkv,
                       bf16_t* __restrict__ q, bf16_t* __restrict__ kn,
                       bf16_t* __restrict__ vn, const int* __restrict__ offp)
{
    const int m = blockIdx.x;            // b*T + t
    const int b = m >> 8, t = m & 255;
    const int tid = threadIdx.x;
    const int c = tid * 8;
    const int h = c >> 7, d0 = c & 127;
    const int pos = offp[0] + t;
    bf16x8 qv = *(const bf16x8*)&qkv[(size_t)m * 6144 + c];
    bf16x8 kv = *(const bf16x8*)&qkv[(size_t)m * 6144 + 2048 + c];
    bf16x8 vv = *(const bf16x8*)&qkv[(size_t)m * 6144 + 4096 + c];
    bf16x8 qo, ko;
    #pragma unroll
    for (int p = 0; p < 4; ++p) {
        const int i = (d0 >> 1) + p;
        const float ang = (float)pos * __expf(-(float)i * 0.14391156861538527f); // ln(1e4)/64
        const float sn = sinf(ang), cs = cosf(ang);
        const float q1 = (float)qv[2 * p], q2 = (float)qv[2 * p + 1];
        const float k1 = (float)kv[2 * p], k2 = (float)kv[2 * p + 1];
        qo[2 * p]     = (bf16_t)(q1 * cs - q2 * sn);
        qo[2 * p + 1] = (bf16_t)(q1 * sn + q2 * cs);
        ko[2 * p]     = (bf16_t)(k1 * cs - k2 * sn);
        ko[2 * p + 1] = (bf16_t)(k1 * sn + k2 * cs);
    }
    const size_t oi = (((size_t)(b * 16 + h) * 256) + t) * 128 + d0;
    *(bf16x8*)&q[oi]  = qo;
    *(bf16x8*)&kn[oi] = ko;
    *(bf16x8*)&vn[oi] = vv;
}

// ---------------- Flash attention, split-S: block = (b,h) x 128-row Q tile x parity ----------------
// Writes UNNORMALIZED partial O (bf16) + per-row m,l (f32); combine kernel merges.
__global__ __launch_bounds__(256)
void attn_kernel(const bf16_t* __restrict__ qh, const bf16_t* __restrict__ kn,
                 const bf16_t* __restrict__ vn, const float* __restrict__ kcache,
                 const float* __restrict__ vcache,
                 bf16_t* __restrict__ Opart, float* __restrict__ mlbuf,
                 const int* __restrict__ offp)
{
    const int T = 256, Dh = 128, CAP = 2048, H = 16;
    const float scale = 0.08838834764831845f;   // 1/sqrt(128)
    __shared__ bf16_t Ks[64][136];    // [s][d], +8 pad (b128 r/w at conflict floor)
    __shared__ bf16_t VtL[128 * 64];  // [d][s] linear, elem = d*64 + ((s>>3)^(d&7))*8 + (s&7)
    __shared__ bf16_t PlL[4][32 * 64];// per-wave P, elem = r*64 + ((c>>3)^(r&7))*8 + (c&7)
    const int bh = blockIdx.x;
    const int tt = blockIdx.y;        // t-tile (0,1)
    const int par = blockIdx.z;       // chunk parity (0,1)
    const int t0 = tt * 128;
    const int b = bh >> 4, h = bh & 15;
    const int offset = offp[0];
    const int Stot = offset + T;      // assumes offset+T <= CAP (holds for given inputs)
    const int tid = threadIdx.x, lane = tid & 63, wid = tid >> 6;
    const int lr = lane & 15, lg = lane >> 4;
    const int tile2 = (bh * 2 + tt) * 2 + par;

    // Q fragments: wave owns rows t0 + wid*32 .. +31
    bf16x8 qf[2][4];
    {
        const bf16_t* qbase = qh + ((size_t)bh * T + t0 + wid * 32) * Dh;
        #pragma unroll
        for (int m = 0; m < 2; ++m)
            #pragma unroll
            for (int ks = 0; ks < 4; ++ks)
                qf[m][ks] = *(const bf16x8*)&qbase[(m * 16 + lr) * Dh + ks * 32 + lg * 8];
    }
    f32x4 accO[2][8] = {};
    float mrun[2][4], lrun[2][4];
    #pragma unroll
    for (int m = 0; m < 2; ++m)
        #pragma unroll
        for (int r = 0; r < 4; ++r) { mrun[m][r] = -3e38f; lrun[m][r] = 0.0f; }

    const int qpos_max = offset + t0 + 127;
    int smax = qpos_max + 1; if (smax > Stot) smax = Stot;
    const int nch = (smax + 63) >> 6;

    // V staging decomposition: thread covers column d, 4 groups of 8 s-values
    const int dcol = tid & 127;
    const int sg0  = (tid >> 7) * 8;   // 0 or 8

    for (int ch = par; ch < nch; ch += 2) {
        const int s0 = ch * 64;
        __syncthreads();
        // ---- stage K row-major (b128 writes) ----
        #pragma unroll
        for (int it = 0; it < 4; ++it) {
            const int idx = tid + it * 256;          // 64 rows x 16 col-groups
            const int r = idx >> 4, c8 = idx & 15;
            const int s = s0 + r;
            bf16x8 kv8;
            if (s < offset) {
                kv8 = cvt8(&kcache[(((size_t)b * H + h) * CAP + s) * Dh + c8 * 8]);
            } else if (s < Stot) {
                kv8 = *(const bf16x8*)&kn[((size_t)bh * T + (s - offset)) * Dh + c8 * 8];
            } else {
                #pragma unroll
                for (int j = 0; j < 8; ++j) kv8[j] = (bf16_t)0.0f;
            }
            *(bf16x8*)&Ks[r][c8 * 8] = kv8;
        }
        // ---- stage V via column loads -> swizzled [d][s] (b128 writes) ----
        #pragma unroll
        for (int it2 = 0; it2 < 4; ++it2) {
            const int sl = sg0 + it2 * 16;           // local s base: {0,8}+{0,16,32,48}
            const int sA = s0 + sl;
            float vv[8];
            if (sA + 7 < offset) {
                const float* vp = &vcache[(((size_t)b * H + h) * CAP + sA) * Dh + dcol];
                #pragma unroll
                for (int j = 0; j < 8; ++j) vv[j] = vp[(size_t)j * Dh];
            } else {
                #pragma unroll
                for (int j = 0; j < 8; ++j) {
                    const int s = sA + j;
                    if (s < offset)    vv[j] = vcache[(((size_t)b * H + h) * CAP + s) * Dh + dcol];
                    else if (s < Stot) vv[j] = (float)vn[((size_t)bh * T + (s - offset)) * Dh + dcol];
                    else               vv[j] = 0.0f;
                }
            }
            bf16x8 v8;
            #pragma unroll
            for (int j = 0; j < 8; ++j) v8[j] = (bf16_t)vv[j];
            *(bf16x8*)&VtL[dcol * 64 + (((sl >> 3) ^ (dcol & 7)) << 3)] = v8;
        }
        __syncthreads();

        // ---- QK^T ----
        f32x4 sc[2][4] = {};
        #pragma unroll
        for (int ks = 0; ks < 4; ++ks) {
            bf16x8 kf[4];
            #pragma unroll
            for (int n = 0; n < 4; ++n)
                kf[n] = *(const bf16x8*)&Ks[n * 16 + lr][ks * 32 + lg * 8];
            #pragma unroll
            for (int m = 0; m < 2; ++m)
                #pragma unroll
                for (int n = 0; n < 4; ++n)
                    sc[m][n] = MFMA(qf[m][ks], kf[n], sc[m][n]);
        }

        // ---- mask + online softmax (defer-max THR=8) ----
        #pragma unroll
        for (int m = 0; m < 2; ++m) {
            #pragma unroll
            for (int r = 0; r < 4; ++r) {
                const int row = m * 16 + lg * 4 + r;          // within wave's 32
                const int qpos = offset + t0 + wid * 32 + row;
                float mx = -3e38f;
                #pragma unroll
                for (int n = 0; n < 4; ++n) {
                    const int sabs = s0 + n * 16 + lr;
                    float v = sc[m][n][r] * scale;
                    v = (sabs <= qpos && sabs < Stot) ? v : -1e30f;
                    sc[m][n][r] = v;
                    mx = fmaxf(mx, v);
                }
                #pragma unroll
                for (int d = 8; d >= 1; d >>= 1) mx = fmaxf(mx, __shfl_xor(mx, d));
                const float mo = mrun[m][r];
                float mn2 = mo;
                if (__any(mx > mo + 8.0f)) {                  // T13: rescale only on real growth
                    mn2 = fmaxf(mo, mx);
                    const float al = __expf(mo - mn2);
                    mrun[m][r] = mn2;
                    lrun[m][r] *= al;
                    #pragma unroll
                    for (int df = 0; df < 8; ++df) accO[m][df][r] *= al;
                }
                float rsum = 0.0f;
                #pragma unroll
                for (int n = 0; n < 4; ++n) {
                    const float p = __expf(sc[m][n][r] - mn2);
                    sc[m][n][r] = p;
                    rsum += p;
                }
                #pragma unroll
                for (int d = 8; d >= 1; d >>= 1) rsum += __shfl_xor(rsum, d);
                lrun[m][r] += rsum;
                // P write, swizzled (col = n*16+lr, row)
                #pragma unroll
                for (int n = 0; n < 4; ++n)
                    PlL[wid][row * 64 + (((n * 2 + (lr >> 3)) ^ (row & 7)) << 3) + (lr & 7)]
                        = (bf16_t)sc[m][n][r];
            }
        }
        asm volatile("s_waitcnt lgkmcnt(0)" ::: "memory");
        __builtin_amdgcn_sched_barrier(0);

        // ---- PV ----
        #pragma unroll
        for (int ks2 = 0; ks2 < 2; ++ks2) {
            bf16x8 pa[2];
            #pragma unroll
            for (int m = 0; m < 2; ++m)
                pa[m] = *(const bf16x8*)&PlL[wid][(m * 16 + lr) * 64 + (((ks2 * 4 + lg) ^ (lr & 7)) << 3)];
            #pragma unroll
            for (int df = 0; df < 8; ++df) {
                const bf16x8 vb = *(const bf16x8*)&VtL[(df * 16 + lr) * 64 + (((ks2 * 4 + lg) ^ (lr & 7)) << 3)];
                #pragma unroll
                for (int m = 0; m < 2; ++m)
                    accO[m][df] = MFMA(pa[m], vb, accO[m][df]);
            }
        }
    }

    // ---- write unnormalized partial O (bf16) + m,l (f32) ----
    const size_t obase = (size_t)tile2 * 128 * 128;
    #pragma unroll
    for (int m = 0; m < 2; ++m)
        #pragma unroll
        for (int df = 0; df < 8; ++df)
            #pragma unroll
            for (int r = 0; r < 4; ++r) {
                const int row = wid * 32 + m * 16 + lg * 4 + r;
                Opart[obase + (size_t)row * 128 + df * 16 + lr] = (bf16_t)accO[m][df][r];
            }
    if (lr == 0) {
        #pragma unroll
        for (int m = 0; m < 2; ++m)
            #pragma unroll
            for (int r = 0; r < 4; ++r) {
                const int row = wid * 32 + m * 16 + lg * 4 + r;
                mlbuf[(size_t)tile2 * 256 + row]       = mrun[m][r];
                mlbuf[(size_t)tile2 * 256 + 128 + row] = lrun[m][r];
            }
    }
}

// ---------------- combine two split-S partials -> o[b][t][h*128+d] ----------------
__global__ __launch_bounds__(256)
void attn_combine_kernel(const bf16_t* __restrict__ Op, const float* __restrict__ ml,
                         bf16_t* __restrict__ outp)
{
    const int tile = blockIdx.x;                 // bh*2 + tt
    const int bh = tile >> 1, tt = tile & 1;
    const int b = bh >> 4, h = bh & 15;
    const int row = threadIdx.x >> 1;
    const int d0 = (threadIdx.x & 1) * 64;
    const int t20 = tile * 2, t21 = tile * 2 + 1;
    const float m0 = ml[(size_t)t20 * 256 + row], l0 = ml[(size_t)t20 * 256 + 128 + row];
    const float m1 = ml[(size_t)t21 * 256 + row], l1 = ml[(size_t)t21 * 256 + 128 + row];
    const float mm = fmaxf(m0, m1);
    const float w0 = __expf(m0 - mm), w1 = __expf(m1 - mm);
    const float den = l0 * w0 + l1 * w1;
    const float s0 = w0 / den, s1 = w1 / den;
    const size_t b0 = (size_t)t20 * 16384 + (size_t)row * 128 + d0;
    const size_t b1 = (size_t)t21 * 16384 + (size_t)row * 128 + d0;
    const int t = tt * 128 + row;
    bf16_t* op = &outp[((size_t)b * 256 + t) * 2048 + h * 128 + d0];
    #pragma unroll
    for (int j = 0; j < 8; ++j) {
        bf16x8 a = *(const bf16x8*)&Op[b0 + j * 8];
        bf16x8 c = *(const bf16x8*)&Op[b1 + j * 8];
        bf16x8 o;
        #pragma unroll
        for (int e = 0; e < 8; ++e) o[e] = (bf16_t)((float)a[e] * s0 + (float)c[e] * s1);
        *(bf16x8*)&op[j * 8] = o;
    }
}

// ---------------- launch ----------------
extern "C" void kernel_launch(void* const* d_in, const int* in_sizes, int n_in,
                              void* d_out, int out_size, void* d_ws, size_t ws_size,
                              hipStream_t stream)
{
    const float* x    = (const float*)d_in[0];
    const float* kc   = (const float*)d_in[1];
    const float* vc   = (const float*)d_in[2];
    const float* wqkv = (const float*)d_in[3];
    const float* wo   = (const float*)d_in[4];
    const float* a1   = (const float*)d_in[5];
    const float* a2   = (const float*)d_in[6];
    const float* w1   = (const float*)d_in[7];
    const float* w2   = (const float*)d_in[8];
    const int*   offp = (const int*)d_in[9];
    float* out = (float*)d_out;

    char* ws = (char*)d_ws;
    // region map, peak 64 MiB:
    // phase A: xn[0,8) wqkv_b[8,32) qkv[32,56)
    // phase B: ml[0,1) q[8,16) kn[16,24) vn[24,32) wo_b[32,40) o[40,48) Opart[48,64)
    // phase C: hbuf[0,8) w1b[8,24) g_h[24,40) w2b[40,56)
    bf16_t* xn     = (bf16_t*)(ws + 0);
    bf16_t* wqkv_b = (bf16_t*)(ws + (8ull  << 20));
    bf16_t* qkv    = (bf16_t*)(ws + (32ull << 20));
    float*  mlbuf  = (float*) (ws + 0);
    bf16_t* q      = (bf16_t*)(ws + (8ull  << 20));
    bf16_t* kn     = (bf16_t*)(ws + (16ull << 20));
    bf16_t* vn     = (bf16_t*)(ws + (24ull << 20));
    bf16_t* wo_b   = (bf16_t*)(ws + (32ull << 20));
    bf16_t* o      = (bf16_t*)(ws + (40ull << 20));
    bf16_t* Opart  = (bf16_t*)(ws + (48ull << 20));
    bf16_t* hbuf   = (bf16_t*)(ws + 0);
    bf16_t* w1b    = (bf16_t*)(ws + (8ull  << 20));
    bf16_t* g_h    = (bf16_t*)(ws + (24ull << 20));
    bf16_t* w2b    = (bf16_t*)(ws + (40ull << 20));

    // 1. xn = rmsnorm(x, a1); convert wqkv
    rmsnorm_kernel<<<2048, 256, 0, stream>>>(x, a1, xn);
    cvt_rows_kernel<<<6144, 256, 0, stream>>>(wqkv, wqkv_b, 2048, 2048);
    // 2. qkv = xn @ wqkv^T (bf16)
    gemm_bb<3><<<dim3(48, 16), 256, 0, stream>>>(xn, wqkv_b, nullptr, qkv, nullptr, 2048, 6144, 2048);
    // 3. rope + split; convert wo
    rope_split_kernel<<<2048, 256, 0, stream>>>(qkv, q, kn, vn, offp);
    cvt_rows_kernel<<<2048, 256, 0, stream>>>(wo, wo_b, 2048, 2048);
    // 4. attention (split-S partials) + combine -> o (bf16 [B,T,C])
    attn_kernel<<<dim3(128, 2, 2), 256, 0, stream>>>(q, kn, vn, kc, vc, Opart, mlbuf, offp);
    attn_combine_kernel<<<256, 256, 0, stream>>>(Opart, mlbuf, o);
    // 5. d_out = x + o @ wo^T
    gemm_bb<1><<<dim3(16, 16), 256, 0, stream>>>(o, wo_b, out, nullptr, x, 2048, 2048, 2048);
    // 6. hbuf = rmsnorm(d_out, a2)
    rmsnorm_kernel<<<2048, 256, 0, stream>>>(out, a2, hbuf);
    // 7-8. FF in two FF/2 passes
    for (int hh = 0; hh < 2; ++hh) {
        cvt_rows_kernel<<<4096, 256, 0, stream>>>(w1 + (size_t)hh * 4096 * 2048, w1b, 2048, 2048);
        gemm_bb<2><<<dim3(32, 16), 256, 0, stream>>>(hbuf, w1b, nullptr, g_h, nullptr, 2048, 4096, 2048);
        cvt_rows_kernel<<<2048, 256, 0, stream>>>(w2 + (size_t)hh * 4096, w2b, 4096, 8192);
        gemm_bb<1><<<dim3(16, 16), 256, 0, stream>>>(g_h, w2b, out, nullptr, out, 2048, 2048, 4096);
    }
}

// Round 5
// 553.073 us; speedup vs baseline: 1.2987x; 1.2987x over previous
//
#include <hip/hip_runtime.h>
#include <math.h>

// StreamingTransformerLayer on MI355X (gfx950).  Round 5.
// B=8 T=256 C=2048 H=16 Dh=128 CAP=2048 FF=8192, offset read on-device.
// R5: attn reverted to R3 structure (R4 split-S + V-col staging regressed).
//     GEMM occupancy attack: split-K x2 for out-proj and fc2 halves (bf16
//     partials + reduce kernel); if ws_size >= 137 MiB, FF runs unsplit
//     (fc1 grid 1024 = 4 blk/CU, fc2 split-K x4 grid 1024).

typedef __bf16 bf16_t;
typedef __bf16 bf16x8 __attribute__((ext_vector_type(8)));
typedef float  f32x4  __attribute__((ext_vector_type(4)));

#define MFMA(a, b, c) __builtin_amdgcn_mfma_f32_16x16x32_bf16((a), (b), (c), 0, 0, 0)

static __device__ __forceinline__ bf16x8 cvt8(const float* __restrict__ src) {
    f32x4 f0 = *(const f32x4*)src;
    f32x4 f1 = *(const f32x4*)(src + 4);
    bf16x8 v;
    v[0] = (bf16_t)f0[0]; v[1] = (bf16_t)f0[1]; v[2] = (bf16_t)f0[2]; v[3] = (bf16_t)f0[3];
    v[4] = (bf16_t)f1[0]; v[5] = (bf16_t)f1[1]; v[6] = (bf16_t)f1[2]; v[7] = (bf16_t)f1[3];
    return v;
}

// async global->LDS, 16B per lane; lds base must be wave-uniform
static __device__ __forceinline__ void gload16(const bf16_t* g, bf16_t* lds) {
    __builtin_amdgcn_global_load_lds(
        (const __attribute__((address_space(1))) void*)g,
        (__attribute__((address_space(3))) void*)lds, 16, 0, 0);
}

// ---------------- weight convert: rows x cols, row stride (f32 -> bf16) ----------------
__global__ __launch_bounds__(256)
void cvt_rows_kernel(const float* __restrict__ src, bf16_t* __restrict__ dst,
                     int cols, int src_stride)
{
    const int row = blockIdx.x;
    const float* s = src + (size_t)row * src_stride;
    bf16_t* d = dst + (size_t)row * cols;
    for (int c = threadIdx.x * 8; c < cols; c += blockDim.x * 8)
        *(bf16x8*)&d[c] = cvt8(&s[c]);
}

// ---------------- RMSNorm: one block per row of 2048 f32, out bf16 ----------------
__global__ __launch_bounds__(256)
void rmsnorm_kernel(const float* __restrict__ x, const float* __restrict__ alpha,
                    bf16_t* __restrict__ out)
{
    const int C = 2048;
    const int row = blockIdx.x;
    const int tid = threadIdx.x;
    const float* xr = x + (size_t)row * C;
    f32x4 a0 = *(const f32x4*)&xr[tid * 8];
    f32x4 a1 = *(const f32x4*)&xr[tid * 8 + 4];
    float ss = a0[0]*a0[0] + a0[1]*a0[1] + a0[2]*a0[2] + a0[3]*a0[3]
             + a1[0]*a1[0] + a1[1]*a1[1] + a1[2]*a1[2] + a1[3]*a1[3];
    #pragma unroll
    for (int d = 32; d >= 1; d >>= 1) ss += __shfl_xor(ss, d);
    __shared__ float red[4];
    const int lane = tid & 63, wid = tid >> 6;
    if (lane == 0) red[wid] = ss;
    __syncthreads();
    const float tot = red[0] + red[1] + red[2] + red[3];
    const float rs = rsqrtf(1e-5f + tot * (1.0f / C));
    f32x4 l0 = *(const f32x4*)&alpha[tid * 8];
    f32x4 l1 = *(const f32x4*)&alpha[tid * 8 + 4];
    bf16x8 o8;
    o8[0] = (bf16_t)(a0[0] * l0[0] * rs); o8[1] = (bf16_t)(a0[1] * l0[1] * rs);
    o8[2] = (bf16_t)(a0[2] * l0[2] * rs); o8[3] = (bf16_t)(a0[3] * l0[3] * rs);
    o8[4] = (bf16_t)(a1[0] * l1[0] * rs); o8[5] = (bf16_t)(a1[1] * l1[1] * rs);
    o8[6] = (bf16_t)(a1[2] * l1[2] * rs); o8[7] = (bf16_t)(a1[3] * l1[7 - 7] * rs * 0.0f + a1[3] * l1[3] * rs); // keep simple: see below
    // (rewritten cleanly below to avoid the hack)
    o8[7] = (bf16_t)(a1[3] * l1[3] * rs);
    *(bf16x8*)&out[(size_t)row * C + tid * 8] = o8;
}

// ---------------- GEMM (m97 structure): C[M,N] = A[M,K] * B[N,K]^T, both bf16 ----------------
// lda/ldb = row strides of A/B.  NSPLIT>1: blockIdx.z selects K-slice of length K,
// A/B advanced by z*K, bf16 partial written at Cb + z*M*N.
// EPI: 0 f32 | 1 res+acc f32 | 2 gelu bf16 | 3 bf16
template<int EPI, int NSPLIT>
__global__ __launch_bounds__(256)
void gemm_bb(const bf16_t* __restrict__ A, const bf16_t* __restrict__ B,
             float* Cf, bf16_t* Cb, const float* __restrict__ res,
             int M, int N, int K, int lda, int ldb)
{
    __shared__ bf16_t As[128 * 64];
    __shared__ bf16_t Bs[128 * 64];
    if constexpr (NSPLIT > 1) {
        A  += (size_t)blockIdx.z * K;
        B  += (size_t)blockIdx.z * K;
        Cb += (size_t)blockIdx.z * (size_t)M * N;
    }
    // XCD-aware swizzle of flat xy block id (xy grids are multiples of 8)
    const int gx = gridDim.x;
    const int nwg = gx * gridDim.y;
    int bid = blockIdx.y * gx + blockIdx.x;
    bid = (bid & 7) * (nwg >> 3) + (bid >> 3);
    const int n0 = (bid % gx) * 128;
    const int m0 = (bid / gx) * 128;

    const int tid = threadIdx.x;
    const int lane = tid & 63, wid = tid >> 6;
    const int wr = wid >> 1, wc = wid & 1;
    const int lr = lane & 15, lg = lane >> 4;
    const int srow = lane >> 3;
    const int scol = (lane & 7) * 8;
    f32x4 acc[4][4] = {};

    for (int kt = 0; kt < K; kt += 64) {
        __syncthreads();
        #pragma unroll
        for (int it = 0; it < 4; ++it) {
            const int r = wid * 32 + it * 8;
            gload16(&A[(size_t)(m0 + r + srow) * lda + kt + scol], &As[r * 64]);
            gload16(&B[(size_t)(n0 + r + srow) * ldb + kt + scol], &Bs[r * 64]);
        }
        __syncthreads();
        #pragma unroll
        for (int kk = 0; kk < 2; ++kk) {
            bf16x8 af[4], bfr[4];
            #pragma unroll
            for (int m = 0; m < 4; ++m)
                af[m] = *(const bf16x8*)&As[(wr * 64 + m * 16 + lr) * 64 + kk * 32 + lg * 8];
            #pragma unroll
            for (int n = 0; n < 4; ++n)
                bfr[n] = *(const bf16x8*)&Bs[(wc * 64 + n * 16 + lr) * 64 + kk * 32 + lg * 8];
            #pragma unroll
            for (int m = 0; m < 4; ++m)
                #pragma unroll
                for (int n = 0; n < 4; ++n)
                    acc[m][n] = MFMA(af[m], bfr[n], acc[m][n]);
        }
    }
    // epilogue; C/D frag: col=lane&15, row=(lane>>4)*4+reg (m89-verified)
    #pragma unroll
    for (int m = 0; m < 4; ++m) {
        #pragma unroll
        for (int n = 0; n < 4; ++n) {
            const int gmb = m0 + wr * 64 + m * 16 + lg * 4;
            const int gn  = n0 + wc * 64 + n * 16 + lr;
            #pragma unroll
            for (int r = 0; r < 4; ++r) {
                const size_t off = (size_t)(gmb + r) * N + gn;
                const float v = acc[m][n][r];
                if (EPI == 0)      Cf[off] = v;
                else if (EPI == 1) Cf[off] = res[off] + v;
                else if (EPI == 2) Cb[off] = (bf16_t)(0.5f * v * (1.0f + erff(v * 0.70710678118654752f)));
                else               Cb[off] = (bf16_t)v;
            }
        }
    }
}

// ---------------- split-K reduce: out[i] = res[i] + sum_z (f32)p[z*n+i] ----------------
template<int Z>
__global__ __launch_bounds__(256)
void reduce_sk_kernel(const bf16_t* __restrict__ p, const float* __restrict__ res,
                      float* __restrict__ out, int n)
{
    for (int i = (blockIdx.x * 256 + threadIdx.x) * 8; i < n; i += gridDim.x * 256 * 8) {
        f32x4 r0 = *(const f32x4*)&res[i];
        f32x4 r1 = *(const f32x4*)&res[i + 4];
        #pragma unroll
        for (int z = 0; z < Z; ++z) {
            bf16x8 v = *(const bf16x8*)&p[(size_t)z * n + i];
            r0[0] += (float)v[0]; r0[1] += (float)v[1]; r0[2] += (float)v[2]; r0[3] += (float)v[3];
            r1[0] += (float)v[4]; r1[1] += (float)v[5]; r1[2] += (float)v[6]; r1[3] += (float)v[7];
        }
        *(f32x4*)&out[i] = r0;
        *(f32x4*)&out[i + 4] = r1;
    }
}

// ---------------- RoPE + split qkv -> q/kn/vn in [B*H][T][Dh] bf16 ----------------
__global__ __launch_bounds__(256)
void rope_split_kernel(const bf16_t* __restrict__ qkv,
                       bf16_t* __restrict__ q, bf16_t* __restrict__ kn,
                       bf16_t* __restrict__ vn, const int* __restrict__ offp)
{
    const int m = blockIdx.x;            // b*T + t
    const int b = m >> 8, t = m & 255;
    const int tid = threadIdx.x;
    const int c = tid * 8;
    const int h = c >> 7, d0 = c & 127;
    const int pos = offp[0] + t;
    bf16x8 qv = *(const bf16x8*)&qkv[(size_t)m * 6144 + c];
    bf16x8 kv = *(const bf16x8*)&qkv[(size_t)m * 6144 + 2048 + c];
    bf16x8 vv = *(const bf16x8*)&qkv[(size_t)m * 6144 + 4096 + c];
    bf16x8 qo, ko;
    #pragma unroll
    for (int p = 0; p < 4; ++p) {
        const int i = (d0 >> 1) + p;
        const float ang = (float)pos * __expf(-(float)i * 0.14391156861538527f); // ln(1e4)/64
        const float sn = sinf(ang), cs = cosf(ang);
        const float q1 = (float)qv[2 * p], q2 = (float)qv[2 * p + 1];
        const float k1 = (float)kv[2 * p], k2 = (float)kv[2 * p + 1];
        qo[2 * p]     = (bf16_t)(q1 * cs - q2 * sn);
        qo[2 * p + 1] = (bf16_t)(q1 * sn + q2 * cs);
        ko[2 * p]     = (bf16_t)(k1 * cs - k2 * sn);
        ko[2 * p + 1] = (bf16_t)(k1 * sn + k2 * cs);
    }
    const size_t oi = (((size_t)(b * 16 + h) * 256) + t) * 128 + d0;
    *(bf16x8*)&q[oi]  = qo;
    *(bf16x8*)&kn[oi] = ko;
    *(bf16x8*)&vn[oi] = vv;
}

// ---------------- Flash attention (R3 structure): block = (b,h) x 128-row Q tile ----------------
__global__ __launch_bounds__(256)
void attn_kernel(const bf16_t* __restrict__ qh, const bf16_t* __restrict__ kn,
                 const bf16_t* __restrict__ vn, const float* __restrict__ kcache,
                 const float* __restrict__ vcache, bf16_t* __restrict__ outp,
                 const int* __restrict__ offp)
{
    const int T = 256, Dh = 128, CAP = 2048, H = 16;
    const float scale = 0.08838834764831845f;   // 1/sqrt(128)
    __shared__ bf16_t Ks[64][136];   // [s_local][d], +8 pad
    __shared__ bf16_t Vt[128][72];   // [d][s_local], +8 pad
    __shared__ bf16_t Pl[4][32][72]; // per-wave P relayout buffer
    const int bh = blockIdx.x;
    const int t0 = blockIdx.y * 128;
    const int b = bh >> 4, h = bh & 15;
    const int offset = offp[0];
    const int Stot = offset + T;     // assumes offset+T <= CAP (holds for given inputs)
    const int tid = threadIdx.x, lane = tid & 63, wid = tid >> 6;
    const int lr = lane & 15, lg = lane >> 4;

    bf16x8 qf[2][4];
    {
        const bf16_t* qbase = qh + ((size_t)bh * T + t0 + wid * 32) * Dh;
        #pragma unroll
        for (int m = 0; m < 2; ++m)
            #pragma unroll
            for (int ks = 0; ks < 4; ++ks)
                qf[m][ks] = *(const bf16x8*)&qbase[(m * 16 + lr) * Dh + ks * 32 + lg * 8];
    }
    f32x4 accO[2][8] = {};
    float mrun[2][4], lrun[2][4];
    #pragma unroll
    for (int m = 0; m < 2; ++m)
        #pragma unroll
        for (int r = 0; r < 4; ++r) { mrun[m][r] = -3e38f; lrun[m][r] = 0.0f; }

    const int qpos_max = offset + t0 + 127;
    int smax = qpos_max + 1; if (smax > Stot) smax = Stot;
    const int nch = (smax + 63) >> 6;

    for (int ch = 0; ch < nch; ++ch) {
        const int s0 = ch * 64;
        __syncthreads();
        #pragma unroll
        for (int it = 0; it < 4; ++it) {
            const int idx = tid + it * 256;          // 64 rows x 16 col-groups
            const int r = idx >> 4, c8 = idx & 15;
            const int s = s0 + r;
            bf16x8 kv8, vv8;
            if (s < offset) {
                const size_t base = (((size_t)b * H + h) * CAP + s) * Dh + c8 * 8;
                kv8 = cvt8(&kcache[base]);
                vv8 = cvt8(&vcache[base]);
            } else if (s < Stot) {
                const size_t base = ((size_t)bh * T + (s - offset)) * Dh + c8 * 8;
                kv8 = *(const bf16x8*)&kn[base];
                vv8 = *(const bf16x8*)&vn[base];
            } else {
                #pragma unroll
                for (int j = 0; j < 8; ++j) { kv8[j] = (bf16_t)0.0f; vv8[j] = (bf16_t)0.0f; }
            }
            *(bf16x8*)&Ks[r][c8 * 8] = kv8;
            #pragma unroll
            for (int j = 0; j < 8; ++j) Vt[c8 * 8 + j][r] = vv8[j];
        }
        __syncthreads();

        f32x4 sc[2][4] = {};
        #pragma unroll
        for (int ks = 0; ks < 4; ++ks) {
            bf16x8 kf[4];
            #pragma unroll
            for (int n = 0; n < 4; ++n)
                kf[n] = *(const bf16x8*)&Ks[n * 16 + lr][ks * 32 + lg * 8];
            #pragma unroll
            for (int m = 0; m < 2; ++m)
                #pragma unroll
                for (int n = 0; n < 4; ++n)
                    sc[m][n] = MFMA(qf[m][ks], kf[n], sc[m][n]);
        }

        #pragma unroll
        for (int m = 0; m < 2; ++m) {
            #pragma unroll
            for (int r = 0; r < 4; ++r) {
                const int qpos = offset + t0 + wid * 32 + m * 16 + lg * 4 + r;
                float mx = -3e38f;
                #pragma unroll
                for (int n = 0; n < 4; ++n) {
                    const int sabs = s0 + n * 16 + lr;
                    float v = sc[m][n][r] * scale;
                    v = (sabs <= qpos && sabs < Stot) ? v : -1e30f;
                    sc[m][n][r] = v;
                    mx = fmaxf(mx, v);
                }
                #pragma unroll
                for (int d = 8; d >= 1; d >>= 1) mx = fmaxf(mx, __shfl_xor(mx, d));
                const float mo = mrun[m][r];
                const float mn2 = fmaxf(mo, mx);
                const float al = __expf(mo - mn2);
                mrun[m][r] = mn2;
                lrun[m][r] *= al;
                #pragma unroll
                for (int df = 0; df < 8; ++df) accO[m][df][r] *= al;
                float rsum = 0.0f;
                #pragma unroll
                for (int n = 0; n < 4; ++n) {
                    const float p = __expf(sc[m][n][r] - mn2);
                    sc[m][n][r] = p;
                    rsum += p;
                }
                #pragma unroll
                for (int d = 8; d >= 1; d >>= 1) rsum += __shfl_xor(rsum, d);
                lrun[m][r] += rsum;
                #pragma unroll
                for (int n = 0; n < 4; ++n)
                    Pl[wid][m * 16 + lg * 4 + r][n * 16 + lr] = (bf16_t)sc[m][n][r];
            }
        }
        asm volatile("s_waitcnt lgkmcnt(0)" ::: "memory");
        __builtin_amdgcn_sched_barrier(0);

        #pragma unroll
        for (int ks2 = 0; ks2 < 2; ++ks2) {
            bf16x8 pa[2];
            #pragma unroll
            for (int m = 0; m < 2; ++m)
                pa[m] = *(const bf16x8*)&Pl[wid][m * 16 + lr][ks2 * 32 + lg * 8];
            #pragma unroll
            for (int df = 0; df < 8; ++df) {
                const bf16x8 vb = *(const bf16x8*)&Vt[df * 16 + lr][ks2 * 32 + lg * 8];
                #pragma unroll
                for (int m = 0; m < 2; ++m)
                    accO[m][df] = MFMA(pa[m], vb, accO[m][df]);
            }
        }
    }

    #pragma unroll
    for (int m = 0; m < 2; ++m) {
        float rinv[4];
        #pragma unroll
        for (int r = 0; r < 4; ++r) rinv[r] = 1.0f / lrun[m][r];
        #pragma unroll
        for (int df = 0; df < 8; ++df) {
            #pragma unroll
            for (int r = 0; r < 4; ++r) {
                const int t = t0 + wid * 32 + m * 16 + lg * 4 + r;
                outp[((size_t)b * 256 + t) * 2048 + h * 128 + df * 16 + lr] =
                    (bf16_t)(accO[m][df][r] * rinv[r]);
            }
        }
    }
}

// ---------------- launch ----------------
extern "C" void kernel_launch(void* const* d_in, const int* in_sizes, int n_in,
                              void* d_out, int out_size, void* d_ws, size_t ws_size,
                              hipStream_t stream)
{
    const float* x    = (const float*)d_in[0];
    const float* kc   = (const float*)d_in[1];
    const float* vc   = (const float*)d_in[2];
    const float* wqkv = (const float*)d_in[3];
    const float* wo   = (const float*)d_in[4];
    const float* a1   = (const float*)d_in[5];
    const float* a2   = (const float*)d_in[6];
    const float* w1   = (const float*)d_in[7];
    const float* w2   = (const float*)d_in[8];
    const int*   offp = (const int*)d_in[9];
    float* out = (float*)d_out;

    char* ws = (char*)d_ws;
    // phase A: xn[0,8) wqkv_b[8,32) qkv[32,56)
    // phase B: q[8,16) kn[16,24) vn[24,32) wo_b[32,40) o[40,48) oprt[48,64)
    // phase C (fallback FF/2): hbuf[0,8) w1b[8,24) g_h[24,40) w2b[40,56); fc2 partials reuse [8,24)
    // phase C (big ws):        hbuf[0,8) w1b[8,40) g[40,72) w2b[72,104) fc2 partials[104,136)
    bf16_t* xn     = (bf16_t*)(ws + 0);
    bf16_t* wqkv_b = (bf16_t*)(ws + (8ull  << 20));
    bf16_t* qkv    = (bf16_t*)(ws + (32ull << 20));
    bf16_t* q      = (bf16_t*)(ws + (8ull  << 20));
    bf16_t* kn     = (bf16_t*)(ws + (16ull << 20));
    bf16_t* vn     = (bf16_t*)(ws + (24ull << 20));
    bf16_t* wo_b   = (bf16_t*)(ws + (32ull << 20));
    bf16_t* o      = (bf16_t*)(ws + (40ull << 20));
    bf16_t* oprt   = (bf16_t*)(ws + (48ull << 20));   // out-proj split-K partials, 2 x 8 MiB
    bf16_t* hbuf   = (bf16_t*)(ws + 0);
    const bool bigws = ws_size >= (137ull << 20);

    // 1. xn = rmsnorm(x, a1); convert wqkv
    rmsnorm_kernel<<<2048, 256, 0, stream>>>(x, a1, xn);
    cvt_rows_kernel<<<6144, 256, 0, stream>>>(wqkv, wqkv_b, 2048, 2048);
    // 2. qkv = xn @ wqkv^T (bf16)
    gemm_bb<3, 1><<<dim3(48, 16), 256, 0, stream>>>(xn, wqkv_b, nullptr, qkv, nullptr,
                                                    2048, 6144, 2048, 2048, 2048);
    // 3. rope + split; convert wo
    rope_split_kernel<<<2048, 256, 0, stream>>>(qkv, q, kn, vn, offp);
    cvt_rows_kernel<<<2048, 256, 0, stream>>>(wo, wo_b, 2048, 2048);
    // 4. attention -> o (bf16 [B,T,C])
    attn_kernel<<<dim3(128, 2), 256, 0, stream>>>(q, kn, vn, kc, vc, o, offp);
    // 5. out-proj split-K x2: partials then d_out = x + p0 + p1
    gemm_bb<3, 2><<<dim3(16, 16, 2), 256, 0, stream>>>(o, wo_b, nullptr, oprt, nullptr,
                                                       2048, 2048, 1024, 2048, 2048);
    reduce_sk_kernel<2><<<2048, 256, 0, stream>>>(oprt, x, out, 2048 * 2048);
    // 6. hbuf = rmsnorm(d_out, a2)
    rmsnorm_kernel<<<2048, 256, 0, stream>>>(out, a2, hbuf);

    if (bigws) {
        // 7-8 full FF: fc1 grid 1024 (4/CU), fc2 split-K x4 grid 1024
        bf16_t* w1b = (bf16_t*)(ws + (8ull   << 20));   // 32 MiB
        bf16_t* g   = (bf16_t*)(ws + (40ull  << 20));   // 32 MiB
        bf16_t* w2b = (bf16_t*)(ws + (72ull  << 20));   // 32 MiB
        bf16_t* prt = (bf16_t*)(ws + (104ull << 20));   // 4 x 8 MiB
        cvt_rows_kernel<<<8192, 256, 0, stream>>>(w1, w1b, 2048, 2048);
        gemm_bb<2, 1><<<dim3(64, 16), 256, 0, stream>>>(hbuf, w1b, nullptr, g, nullptr,
                                                        2048, 8192, 2048, 2048, 2048);
        cvt_rows_kernel<<<2048, 256, 0, stream>>>(w2, w2b, 8192, 8192);
        gemm_bb<3, 4><<<dim3(16, 16, 4), 256, 0, stream>>>(g, w2b, nullptr, prt, nullptr,
                                                           2048, 2048, 2048, 8192, 8192);
        reduce_sk_kernel<4><<<2048, 256, 0, stream>>>(prt, out, out, 2048 * 2048);
    } else {
        // 7-8 FF in two FF/2 passes; fc2h split-K x2 (partials reuse w1b region)
        bf16_t* w1b = (bf16_t*)(ws + (8ull  << 20));    // 16 MiB
        bf16_t* g_h = (bf16_t*)(ws + (24ull << 20));    // 16 MiB
        bf16_t* w2b = (bf16_t*)(ws + (40ull << 20));    // 16 MiB
        bf16_t* prt = (bf16_t*)(ws + (8ull  << 20));    // 2 x 8 MiB (w1b dead by then)
        for (int hh = 0; hh < 2; ++hh) {
            cvt_rows_kernel<<<4096, 256, 0, stream>>>(w1 + (size_t)hh * 4096 * 2048, w1b, 2048, 2048);
            gemm_bb<2, 1><<<dim3(32, 16), 256, 0, stream>>>(hbuf, w1b, nullptr, g_h, nullptr,
                                                            2048, 4096, 2048, 2048, 2048);
            cvt_rows_kernel<<<2048, 256, 0, stream>>>(w2 + (size_t)hh * 4096, w2b, 4096, 8192);
            gemm_bb<3, 2><<<dim3(16, 16, 2), 256, 0, stream>>>(g_h, w2b, nullptr, prt, nullptr,
                                                               2048, 2048, 2048, 4096, 4096);
            reduce_sk_kernel<2><<<2048, 256, 0, stream>>>(prt, out, out, 2048 * 2048);
        }
    }
}